// Round 6
// baseline (262.539 us; speedup 1.0000x reference)
//
#include <hip/hip_runtime.h>
#include <math.h>

#define B_    4
#define CIN_  32
#define COUT_ 64
#define H_    192
#define W_    192
#define HW_   (H_ * W_)        // 36864
#define NPIX_ (B_ * HW_)       // 147456
#define EPS_  1e-5f

typedef _Float16 half8 __attribute__((ext_vector_type(8)));
typedef float    f32x4 __attribute__((ext_vector_type(4)));

#define WTN_ 18432             // halves per wt_def plane (hi, then lo)

// XCD-aware swizzle (proven R7): XCD k owns a contiguous half-image-plane.
static __device__ __forceinline__ int swz2304(int blk) {
    return ((blk & 7) * 288) + (blk >> 3);
}

// ---------------------------------------------------------------------------
// Kernel 0: fused prep.  (UNCHANGED from R5 — passing)
// Blocks [0,576): transpose x (NCHW) -> xt (NHWC) via LDS staging.
// Blocks [576,673): weight transposes + stats zeroing.
// wt_def: SPLIT fp16 (hi at [i], lo at [WTN_+i]), MFMA B-fragment order
//   [kk][ot][lane][j]: o = ot*16 + (lane&15), c = (lane>>4)*8 + j
// wt_off [kk][o20][c32] fp32 (o>=18 zero).
// ---------------------------------------------------------------------------
__global__ __launch_bounds__(256) void k_pre(
    const float* __restrict__ x, const float* __restrict__ w_def,
    const float* __restrict__ w_off, float* __restrict__ xt,
    _Float16* __restrict__ wt_def, float* __restrict__ wt_off,
    float* __restrict__ stats)
{
    if (blockIdx.x < NPIX_ / 256) {
        __shared__ float lds[32 * 257];
        const int tid  = threadIdx.x;
        const int pid0 = blockIdx.x * 256;
        const int b    = pid0 / HW_;           // blocks never straddle b
        const int rem0 = pid0 - b * HW_;
        const float* xb = x + (size_t)b * CIN_ * HW_ + rem0;

#pragma unroll
        for (int c = 0; c < 32; ++c)
            lds[c * 257 + tid] = xb[c * HW_ + tid];
        __syncthreads();

        float4* dst = (float4*)(xt + (size_t)pid0 * 32);
#pragma unroll
        for (int i = 0; i < 8; ++i) {
            const int idx = i * 256 + tid;     // consecutive across lanes
            const int px  = idx >> 3;
            const int q   = idx & 7;
            float4 v;
            v.x = lds[(q * 4 + 0) * 257 + px];
            v.y = lds[(q * 4 + 1) * 257 + px];
            v.z = lds[(q * 4 + 2) * 257 + px];
            v.w = lds[(q * 4 + 3) * 257 + px];
            dst[idx] = v;
        }
    } else {
        const int i = (blockIdx.x - NPIX_ / 256) * 256 + threadIdx.x;
        if (i < WTN_) {                        // wt_def split-fp16 B-fragments
            const int j  = i & 7;
            const int ln = (i >> 3) & 63;
            const int ot = (i >> 9) & 3;
            const int kk = i >> 11;
            const int o  = ot * 16 + (ln & 15);
            const int c  = (ln >> 4) * 8 + j;
            const float wv = w_def[(o * 32 + c) * 9 + kk];
            const _Float16 hi = (_Float16)wv;
            wt_def[i]        = hi;
            wt_def[WTN_ + i] = (_Float16)(wv - (float)hi);
        } else if (i < WTN_ + 5760) {          // wt_off[kk][o20][c32]
            const int e  = i - WTN_;
            const int c  = e & 31;
            const int t  = e >> 5;
            const int o  = t % 20;
            const int kk = t / 20;
            wt_off[e] = (o < 18) ? w_off[(o * 32 + c) * 9 + kk] : 0.f;
        } else if (i < WTN_ + 5760 + 512) {
            stats[i - WTN_ - 5760] = 0.f;      // sum_bc + sumsq_bc
        }
    }
}

// ---------------------------------------------------------------------------
// Kernel 1: FUSED offsets-conv + deformable conv (MFMA) + BN stats.
// R5 post-mortem: latency-bound (occ 37.6%, both pipes idle). Fix = TLP:
//   * Stage A processes channels in TWO 16-ch passes -> tile [4][198]f4 =
//     12,672 B LDS (was 25,344) -> ~2x resident blocks. acc5 carried in regs.
//   * Stage B = R2-PROVEN direct-lane form: lane (lq4,l15) gathers its own
//     (pixel og*16+l15, channels lq4*8..+8) -> A-fragment in registers, no
//     vbuf, NO stage-B barriers -> waves free-run; 6 blocks/CU interleave
//     gathers against MFMA. Gathers fully coalesced (64 lanes span 2KB).
//   * Split-fp16 trio (hi*hi + lo*hi + hi*lo), 12 MFMA/kk — 0.0078 floor.
// ---------------------------------------------------------------------------
__global__ __launch_bounds__(256, 6) void k_fused(
    const float* __restrict__ xt, const float* __restrict__ wto,
    const float* __restrict__ b_off, const _Float16* __restrict__ wtd,
    const float* __restrict__ b_def, float* __restrict__ y,
    float* __restrict__ sum_bc, float* __restrict__ sumsq_bc)
{
    __shared__ __align__(16) float smem[3168];   // 12,672 B
    float4 (*tile)[198] = (float4(*)[198])smem;  // [ch-quad j][r*66+cc] (half)
    float* offlds = smem;                        // [18][64] alias after stage A

    const int tid  = threadIdx.x;
    const int px   = tid & 63;
    const int og   = __builtin_amdgcn_readfirstlane(tid >> 6);  // wave id
    const int lane = tid & 63;                   // == px

    const int blk  = swz2304(blockIdx.x);
    const int base = blk * 64;
    const int b    = base / HW_;
    const int rem0 = base - b * HW_;
    const int h0   = rem0 / W_;
    const int w0   = rem0 - h0 * W_;             // 0, 64, or 128
    const float* xb = xt + (size_t)b * HW_ * 32;

    // ---------------- Stage A: offsets conv (two 16-ch passes) ----------------
    float acc5[5] = {0.f, 0.f, 0.f, 0.f, 0.f};
    const bool rv0 = (h0 - 1 >= 0), rv2 = (h0 + 1 < H_);

#pragma unroll 1
    for (int hf = 0; hf < 2; ++hf) {
        for (int i = tid; i < 792; i += 256) {   // 4 quads x 198 recs
            const int j   = i & 3;
            const int rec = i >> 2;
            const int r   = rec / 66;
            const int cc  = rec - r * 66;
            const int hc  = min(max(h0 + r - 1, 0), H_ - 1);
            const int wc  = min(max(w0 + cc - 1, 0), W_ - 1);
            tile[j][rec] = *(const float4*)(xb + (hc * W_ + wc) * 32 + hf * 16 + j * 4);
        }
        __syncthreads();

#pragma unroll 1
        for (int kk = 0; kk < 9; ++kk) {
            const int ky = kk / 3, kx = kk % 3;
            const bool rok = (ky == 0) ? rv0 : ((ky == 2) ? rv2 : true);
            const int wcol = w0 + px + kx - 1;
            const float g = (rok && wcol >= 0 && wcol < W_) ? 1.f : 0.f;
            const int rec = ky * 66 + px + kx;

            float4 v[4];
#pragma unroll
            for (int j = 0; j < 4; ++j) {
                v[j] = tile[j][rec];
                v[j].x *= g; v[j].y *= g; v[j].z *= g; v[j].w *= g;
            }
            const float* wk = wto + (kk * 20 + og * 5) * 32 + hf * 16;
#pragma unroll
            for (int oo = 0; oo < 5; ++oo) {
                const float4* wr = (const float4*)(wk + oo * 32);
                float s = acc5[oo];
#pragma unroll
                for (int j = 0; j < 4; ++j) {
                    const float4 wv = wr[j];
                    s += v[j].x * wv.x + v[j].y * wv.y
                       + v[j].z * wv.z + v[j].w * wv.w;
                }
                acc5[oo] = s;
            }
        }
        __syncthreads();      // tile reads done (next pass load / offlds alias)
    }

#pragma unroll
    for (int oo = 0; oo < 5; ++oo) {
        const int o = og * 5 + oo;
        if (o < 18) offlds[o * 64 + px] = acc5[oo] + b_off[o];
    }
    __syncthreads();          // offlds ready; NO further barriers

    // ---------------- Stage B: deformable conv via MFMA (R2-proven) ----------
    const int l15 = lane & 15;
    const int lq4 = lane >> 4;                   // channel group / row group
    const int pxl = (og << 4) + l15;             // A-fragment row = pixel
    const int wc_ = w0 + pxl;
    const float* xg = xb + lq4 * 8;              // channels [8*lq4, 8*lq4+8)
    const _Float16* wbh = wtd + lane * 8;        // hi plane
    const _Float16* wbl = wtd + WTN_ + lane * 8; // lo plane

    f32x4 acc[4];
#pragma unroll
    for (int ot = 0; ot < 4; ++ot) acc[ot] = (f32x4){0.f, 0.f, 0.f, 0.f};

#pragma unroll 1
    for (int kk = 0; kk < 9; ++kk) {
        // B fragments first: in flight during offset/gather work
        const _Float16* wkh = wbh + (kk << 11);
        const _Float16* wkl = wbl + (kk << 11);
        const half8 bh0 = *(const half8*)(wkh);
        const half8 bh1 = *(const half8*)(wkh + 512);
        const half8 bh2 = *(const half8*)(wkh + 1024);
        const half8 bh3 = *(const half8*)(wkh + 1536);
        const half8 bl0 = *(const half8*)(wkl);
        const half8 bl1 = *(const half8*)(wkl + 512);
        const half8 bl2 = *(const half8*)(wkl + 1024);
        const half8 bl3 = *(const half8*)(wkl + 1536);

        const float dy = offlds[(2 * kk) * 64 + pxl];      // broadcast reads
        const float dx = offlds[(2 * kk + 1) * 64 + pxl];
        const float py = (float)(h0 + kk / 3 - 1) + dy;
        const float qx = (float)(wc_ + kk % 3 - 1) + dx;
        const float y0f = floorf(py), x0f = floorf(qx);
        const float wy = py - y0f, wx = qx - x0f;
        const int iy0 = (int)y0f, ix0 = (int)x0f;
        const int iy1 = iy0 + 1,  ix1 = ix0 + 1;
        const float vy0 = (iy0 >= 0 && iy0 < H_) ? 1.f : 0.f;
        const float vy1 = (iy1 >= 0 && iy1 < H_) ? 1.f : 0.f;
        const float vx0 = (ix0 >= 0 && ix0 < W_) ? 1.f : 0.f;
        const float vx1 = (ix1 >= 0 && ix1 < W_) ? 1.f : 0.f;
        const float w00 = (1.f - wy) * (1.f - wx) * vy0 * vx0;
        const float w01 = (1.f - wy) * wx * vy0 * vx1;
        const float w10 = wy * (1.f - wx) * vy1 * vx0;
        const float w11 = wy * wx * vy1 * vx1;
        const int cy0 = min(max(iy0, 0), H_ - 1), cy1 = min(max(iy1, 0), H_ - 1);
        const int cx0 = min(max(ix0, 0), W_ - 1), cx1 = min(max(ix1, 0), W_ - 1);
        const int o00 = (cy0 * W_ + cx0) * 32, o01 = (cy0 * W_ + cx1) * 32;
        const int o10 = (cy1 * W_ + cx0) * 32, o11 = (cy1 * W_ + cx1) * 32;

        // wave covers 16 px x 32 ch: each corner spans a contiguous 2KB
        const float4 A0 = *(const float4*)(xg + o00), A1 = *(const float4*)(xg + o00 + 4);
        const float4 B0 = *(const float4*)(xg + o01), B1 = *(const float4*)(xg + o01 + 4);
        const float4 C0 = *(const float4*)(xg + o10), C1 = *(const float4*)(xg + o10 + 4);
        const float4 D0 = *(const float4*)(xg + o11), D1 = *(const float4*)(xg + o11 + 4);

        float v[8];
        v[0] = w00 * A0.x + w01 * B0.x + w10 * C0.x + w11 * D0.x;
        v[1] = w00 * A0.y + w01 * B0.y + w10 * C0.y + w11 * D0.y;
        v[2] = w00 * A0.z + w01 * B0.z + w10 * C0.z + w11 * D0.z;
        v[3] = w00 * A0.w + w01 * B0.w + w10 * C0.w + w11 * D0.w;
        v[4] = w00 * A1.x + w01 * B1.x + w10 * C1.x + w11 * D1.x;
        v[5] = w00 * A1.y + w01 * B1.y + w10 * C1.y + w11 * D1.y;
        v[6] = w00 * A1.z + w01 * B1.z + w10 * C1.z + w11 * D1.z;
        v[7] = w00 * A1.w + w01 * B1.w + w10 * C1.w + w11 * D1.w;

        half8 a_hi, a_lo;
#pragma unroll
        for (int j = 0; j < 8; ++j) {
            const _Float16 h = (_Float16)v[j];
            a_hi[j] = h;
            a_lo[j] = (_Float16)(v[j] - (float)h);
        }

        acc[0] = __builtin_amdgcn_mfma_f32_16x16x32_f16(a_hi, bh0, acc[0], 0, 0, 0);
        acc[1] = __builtin_amdgcn_mfma_f32_16x16x32_f16(a_hi, bh1, acc[1], 0, 0, 0);
        acc[2] = __builtin_amdgcn_mfma_f32_16x16x32_f16(a_hi, bh2, acc[2], 0, 0, 0);
        acc[3] = __builtin_amdgcn_mfma_f32_16x16x32_f16(a_hi, bh3, acc[3], 0, 0, 0);
        acc[0] = __builtin_amdgcn_mfma_f32_16x16x32_f16(a_lo, bh0, acc[0], 0, 0, 0);
        acc[1] = __builtin_amdgcn_mfma_f32_16x16x32_f16(a_lo, bh1, acc[1], 0, 0, 0);
        acc[2] = __builtin_amdgcn_mfma_f32_16x16x32_f16(a_lo, bh2, acc[2], 0, 0, 0);
        acc[3] = __builtin_amdgcn_mfma_f32_16x16x32_f16(a_lo, bh3, acc[3], 0, 0, 0);
        acc[0] = __builtin_amdgcn_mfma_f32_16x16x32_f16(a_hi, bl0, acc[0], 0, 0, 0);
        acc[1] = __builtin_amdgcn_mfma_f32_16x16x32_f16(a_hi, bl1, acc[1], 0, 0, 0);
        acc[2] = __builtin_amdgcn_mfma_f32_16x16x32_f16(a_hi, bl2, acc[2], 0, 0, 0);
        acc[3] = __builtin_amdgcn_mfma_f32_16x16x32_f16(a_hi, bl3, acc[3], 0, 0, 0);
    }

    // epilogue: bias + float4 store + BN stats (R2-proven).
    // D layout: col = lane&15 -> o = ot*16+l15; row = lq4*4+reg -> px.
    const int rem = rem0 + (og << 4) + (lq4 << 2);
    float sred[4], qred[4];
#pragma unroll
    for (int ot = 0; ot < 4; ++ot) {
        const float bias = b_def[ot * 16 + l15];
        f32x4 av = acc[ot];
        av[0] += bias; av[1] += bias; av[2] += bias; av[3] += bias;
        *(f32x4*)(y + ((size_t)(b * COUT_ + ot * 16 + l15)) * HW_ + rem) = av;
        float s = av[0] + av[1] + av[2] + av[3];
        float q = av[0] * av[0] + av[1] * av[1] + av[2] * av[2] + av[3] * av[3];
        s += __shfl_xor(s, 16, 64); s += __shfl_xor(s, 32, 64);
        q += __shfl_xor(q, 16, 64); q += __shfl_xor(q, 32, 64);
        sred[ot] = s; qred[ot] = q;
    }
    // lane (= lq4*16+l15) takes ot = lq4 -> exactly one atomic pair per lane
    float ms = sred[0], mq = qred[0];
    if (lq4 == 1)      { ms = sred[1]; mq = qred[1]; }
    else if (lq4 == 2) { ms = sred[2]; mq = qred[2]; }
    else if (lq4 == 3) { ms = sred[3]; mq = qred[3]; }
    atomicAdd(&sum_bc[b * COUT_ + lane], ms);
    atomicAdd(&sumsq_bc[b * COUT_ + lane], mq);
}

// ---------------------------------------------------------------------------
// Kernel 2: fused SE-MLP + affine(BN*SE) + ReLU + 2x2 maxpool.
// ---------------------------------------------------------------------------
__global__ __launch_bounds__(256) void k_finish(
    const float* __restrict__ y,
    const float* __restrict__ sum_bc, const float* __restrict__ sumsq_bc,
    const float* __restrict__ gamma, const float* __restrict__ beta,
    const float* __restrict__ fc1_w, const float* __restrict__ fc1_b,
    const float* __restrict__ fc2_w, const float* __restrict__ fc2_b,
    float* __restrict__ out)
{
    __shared__ float sal[256], sbb[256], sin_[256];
    const int tid = threadIdx.x;
    {
        const int b = tid >> 6, c = tid & 63;
        float ch_s = 0.f, ch_q = 0.f;
#pragma unroll
        for (int bb = 0; bb < 4; ++bb) {
            ch_s += sum_bc[bb * 64 + c];
            ch_q += sumsq_bc[bb * 64 + c];
        }
        const float invN = 1.f / (float)(B_ * HW_);
        const float mean = ch_s * invN;
        const float var  = ch_q * invN - mean * mean;
        const float a    = gamma[c] * rsqrtf(var + EPS_);
        const float bi   = beta[c] - mean * a;
        sin_[tid] = a * (sum_bc[tid] * (1.f / (float)HW_)) + bi;
        __syncthreads();
        float hv[4];
#pragma unroll
        for (int j = 0; j < 4; ++j) {
            float hs = fc1_b[j];
            for (int cc = 0; cc < 64; ++cc)
                hs += sin_[b * 64 + cc] * fc1_w[j * 64 + cc];
            hv[j] = fmaxf(hs, 0.f);
        }
        float o = fc2_b[c];
#pragma unroll
        for (int j = 0; j < 4; ++j) o += hv[j] * fc2_w[c * 4 + j];
        const float s = 1.f / (1.f + expf(-o));
        sal[tid] = a * s;
        sbb[tid] = bi * s;
    }
    __syncthreads();

    const int t    = blockIdx.x * 256 + tid;
    const int opix = t * 2;
    const int bc   = opix / (96 * 96);
    const int rem  = opix - bc * (96 * 96);
    const int oh   = rem / 96, ow = rem - oh * 96;   // ow even
    const float al = sal[bc], bb = sbb[bc];
    const float* yp = y + (size_t)bc * HW_ + (2 * oh) * W_ + 2 * ow;
    const float4 r0 = *(const float4*)yp;
    const float4 r1 = *(const float4*)(yp + W_);
    float2 st;
    st.x = fmaxf(fmaxf(fmaxf(fmaf(r0.x, al, bb), fmaf(r0.y, al, bb)),
                       fmaxf(fmaf(r1.x, al, bb), fmaf(r1.y, al, bb))), 0.f);
    st.y = fmaxf(fmaxf(fmaxf(fmaf(r0.z, al, bb), fmaf(r0.w, al, bb)),
                       fmaxf(fmaf(r1.z, al, bb), fmaf(r1.w, al, bb))), 0.f);
    *(float2*)(out + opix) = st;
}

// ---------------------------------------------------------------------------
extern "C" void kernel_launch(void* const* d_in, const int* in_sizes, int n_in,
                              void* d_out, int out_size, void* d_ws, size_t ws_size,
                              hipStream_t stream)
{
    const float* x     = (const float*)d_in[0];
    const float* w_off = (const float*)d_in[1];
    const float* b_off = (const float*)d_in[2];
    const float* w_def = (const float*)d_in[3];
    const float* b_def = (const float*)d_in[4];
    const float* gamma = (const float*)d_in[5];
    const float* beta  = (const float*)d_in[6];
    const float* fc1_w = (const float*)d_in[7];
    const float* fc1_b = (const float*)d_in[8];
    const float* fc2_w = (const float*)d_in[9];
    const float* fc2_b = (const float*)d_in[10];
    float* out = (float*)d_out;

    float* ws   = (float*)d_ws;
    float* yb        = ws;                       // 9,437,184 floats
    float* xt        = yb + 9437184;             // 4,718,592 floats (NHWC x)
    _Float16* wt_def = (_Float16*)(xt + 4718592);// 2*18,432 halves (= 18,432 floats)
    float* wt_off    = xt + 4718592 + 18432;     // 5,760
    float* stats     = wt_off + 5760;            // 1,024
    float* sum_bc    = stats;
    float* sumsq_bc  = stats + 256;

    k_pre   <<<dim3(NPIX_ / 256 + 97), dim3(256), 0, stream>>>(
                x, w_def, w_off, xt, wt_def, wt_off, stats);
    k_fused <<<dim3(NPIX_ / 64), dim3(256), 0, stream>>>(
                xt, wt_off, b_off, wt_def, b_def, yb, sum_bc, sumsq_bc);
    k_finish<<<dim3(B_ * COUT_ * 96 * 96 / 512), dim3(256), 0, stream>>>(
                yb, sum_bc, sumsq_bc, gamma, beta,
                fc1_w, fc1_b, fc2_w, fc2_b, out);
}

// Round 7
// 238.191 us; speedup vs baseline: 1.1022x; 1.1022x over previous
//
#include <hip/hip_runtime.h>
#include <math.h>

#define B_    4
#define CIN_  32
#define COUT_ 64
#define H_    192
#define W_    192
#define HW_   (H_ * W_)        // 36864
#define NPIX_ (B_ * HW_)       // 147456
#define EPS_  1e-5f

typedef _Float16 half8 __attribute__((ext_vector_type(8)));
typedef float    f32x4 __attribute__((ext_vector_type(4)));

#define WTN_ 18432             // halves per wt_def plane (hi, then lo)
#define NSTAT_ 4096            // stats floats: sum_part[8][256] + sumsq_part[8][256]

// XCD-aware swizzle (proven R7): XCD k owns a contiguous half-image-plane.
static __device__ __forceinline__ int swz2304(int blk) {
    return ((blk & 7) * 288) + (blk >> 3);
}

// ---------------------------------------------------------------------------
// Kernel 0: fused prep.
// Blocks [0,576): transpose x (NCHW) -> xt (NHWC) via LDS staging.
// Blocks [576,687): weight transposes + stats zeroing (8-sliced stats).
// wt_def: SPLIT fp16 (hi at [i], lo at [WTN_+i]), MFMA B-fragment order
//   [kk][ot][lane][j]: o = ot*16 + (lane&15), c = (lane>>4)*8 + j
// wt_off [kk][o20][c32] fp32 (o>=18 zero).
// ---------------------------------------------------------------------------
__global__ __launch_bounds__(256) void k_pre(
    const float* __restrict__ x, const float* __restrict__ w_def,
    const float* __restrict__ w_off, float* __restrict__ xt,
    _Float16* __restrict__ wt_def, float* __restrict__ wt_off,
    float* __restrict__ stats)
{
    if (blockIdx.x < NPIX_ / 256) {
        __shared__ float lds[32 * 257];
        const int tid  = threadIdx.x;
        const int pid0 = blockIdx.x * 256;
        const int b    = pid0 / HW_;           // blocks never straddle b
        const int rem0 = pid0 - b * HW_;
        const float* xb = x + (size_t)b * CIN_ * HW_ + rem0;

#pragma unroll
        for (int c = 0; c < 32; ++c)
            lds[c * 257 + tid] = xb[c * HW_ + tid];
        __syncthreads();

        float4* dst = (float4*)(xt + (size_t)pid0 * 32);
#pragma unroll
        for (int i = 0; i < 8; ++i) {
            const int idx = i * 256 + tid;     // consecutive across lanes
            const int px  = idx >> 3;
            const int q   = idx & 7;
            float4 v;
            v.x = lds[(q * 4 + 0) * 257 + px];
            v.y = lds[(q * 4 + 1) * 257 + px];
            v.z = lds[(q * 4 + 2) * 257 + px];
            v.w = lds[(q * 4 + 3) * 257 + px];
            dst[idx] = v;
        }
    } else {
        const int i = (blockIdx.x - NPIX_ / 256) * 256 + threadIdx.x;
        if (i < WTN_) {                        // wt_def split-fp16 B-fragments
            const int j  = i & 7;
            const int ln = (i >> 3) & 63;
            const int ot = (i >> 9) & 3;
            const int kk = i >> 11;
            const int o  = ot * 16 + (ln & 15);
            const int c  = (ln >> 4) * 8 + j;
            const float wv = w_def[(o * 32 + c) * 9 + kk];
            const _Float16 hi = (_Float16)wv;
            wt_def[i]        = hi;
            wt_def[WTN_ + i] = (_Float16)(wv - (float)hi);
        } else if (i < WTN_ + 5760) {          // wt_off[kk][o20][c32]
            const int e  = i - WTN_;
            const int c  = e & 31;
            const int t  = e >> 5;
            const int o  = t % 20;
            const int kk = t / 20;
            wt_off[e] = (o < 18) ? w_off[(o * 32 + c) * 9 + kk] : 0.f;
        } else if (i < WTN_ + 5760 + NSTAT_) {
            stats[i - WTN_ - 5760] = 0.f;      // sum_part + sumsq_part (8-sliced)
        }
    }
}

// ---------------------------------------------------------------------------
// Kernel 1: FUSED offsets-conv + deformable conv (MFMA) + BN stats.
// Main path UNCHANGED from R6 (passing, absmax 0.0078).
// EPILOGUE FIXED (R6 post-mortem): the 512 same-address atomics/block were
// the shared ~150us serializer pinning every MFMA variant at 167us.
// Now: cross-wave LDS reduce -> wave 0 only -> atomics sliced 8x by
// blockIdx&7 (~XCD) into sum_part[8][4][64]. 128 atomics/block, 8x the
// target lines -> atomic drain ~5us, fully hidden.
// ---------------------------------------------------------------------------
__global__ __launch_bounds__(256, 6) void k_fused(
    const float* __restrict__ xt, const float* __restrict__ wto,
    const float* __restrict__ b_off, const _Float16* __restrict__ wtd,
    const float* __restrict__ b_def, float* __restrict__ y,
    float* __restrict__ sum_bc, float* __restrict__ sumsq_bc)
{
    __shared__ __align__(16) float smem[3168];   // 12,672 B
    float4 (*tile)[198] = (float4(*)[198])smem;  // [ch-quad j][r*66+cc] (half)
    float* offlds = smem;                        // [18][64] alias after stage A
    float* red_s  = smem + 2048;                 // [4][64] epilogue reduce
    float* red_q  = smem + 2304;                 // [4][64] (disjoint from offlds)

    const int tid  = threadIdx.x;
    const int px   = tid & 63;
    const int og   = __builtin_amdgcn_readfirstlane(tid >> 6);  // wave id
    const int lane = tid & 63;                   // == px

    const int blk  = swz2304(blockIdx.x);
    const int base = blk * 64;
    const int b    = base / HW_;
    const int rem0 = base - b * HW_;
    const int h0   = rem0 / W_;
    const int w0   = rem0 - h0 * W_;             // 0, 64, or 128
    const float* xb = xt + (size_t)b * HW_ * 32;

    // ---------------- Stage A: offsets conv (two 16-ch passes) ----------------
    float acc5[5] = {0.f, 0.f, 0.f, 0.f, 0.f};
    const bool rv0 = (h0 - 1 >= 0), rv2 = (h0 + 1 < H_);

#pragma unroll 1
    for (int hf = 0; hf < 2; ++hf) {
        for (int i = tid; i < 792; i += 256) {   // 4 quads x 198 recs
            const int j   = i & 3;
            const int rec = i >> 2;
            const int r   = rec / 66;
            const int cc  = rec - r * 66;
            const int hc  = min(max(h0 + r - 1, 0), H_ - 1);
            const int wc  = min(max(w0 + cc - 1, 0), W_ - 1);
            tile[j][rec] = *(const float4*)(xb + (hc * W_ + wc) * 32 + hf * 16 + j * 4);
        }
        __syncthreads();

#pragma unroll 1
        for (int kk = 0; kk < 9; ++kk) {
            const int ky = kk / 3, kx = kk % 3;
            const bool rok = (ky == 0) ? rv0 : ((ky == 2) ? rv2 : true);
            const int wcol = w0 + px + kx - 1;
            const float g = (rok && wcol >= 0 && wcol < W_) ? 1.f : 0.f;
            const int rec = ky * 66 + px + kx;

            float4 v[4];
#pragma unroll
            for (int j = 0; j < 4; ++j) {
                v[j] = tile[j][rec];
                v[j].x *= g; v[j].y *= g; v[j].z *= g; v[j].w *= g;
            }
            const float* wk = wto + (kk * 20 + og * 5) * 32 + hf * 16;
#pragma unroll
            for (int oo = 0; oo < 5; ++oo) {
                const float4* wr = (const float4*)(wk + oo * 32);
                float s = acc5[oo];
#pragma unroll
                for (int j = 0; j < 4; ++j) {
                    const float4 wv = wr[j];
                    s += v[j].x * wv.x + v[j].y * wv.y
                       + v[j].z * wv.z + v[j].w * wv.w;
                }
                acc5[oo] = s;
            }
        }
        __syncthreads();      // tile reads done (next pass load / offlds alias)
    }

#pragma unroll
    for (int oo = 0; oo < 5; ++oo) {
        const int o = og * 5 + oo;
        if (o < 18) offlds[o * 64 + px] = acc5[oo] + b_off[o];
    }
    __syncthreads();          // offlds ready

    // ---------------- Stage B: deformable conv via MFMA (R2-proven) ----------
    const int l15 = lane & 15;
    const int lq4 = lane >> 4;                   // channel group / row group
    const int pxl = (og << 4) + l15;             // A-fragment row = pixel
    const int wc_ = w0 + pxl;
    const float* xg = xb + lq4 * 8;              // channels [8*lq4, 8*lq4+8)
    const _Float16* wbh = wtd + lane * 8;        // hi plane
    const _Float16* wbl = wtd + WTN_ + lane * 8; // lo plane

    f32x4 acc[4];
#pragma unroll
    for (int ot = 0; ot < 4; ++ot) acc[ot] = (f32x4){0.f, 0.f, 0.f, 0.f};

#pragma unroll 1
    for (int kk = 0; kk < 9; ++kk) {
        // B fragments first: in flight during offset/gather work
        const _Float16* wkh = wbh + (kk << 11);
        const _Float16* wkl = wbl + (kk << 11);
        const half8 bh0 = *(const half8*)(wkh);
        const half8 bh1 = *(const half8*)(wkh + 512);
        const half8 bh2 = *(const half8*)(wkh + 1024);
        const half8 bh3 = *(const half8*)(wkh + 1536);
        const half8 bl0 = *(const half8*)(wkl);
        const half8 bl1 = *(const half8*)(wkl + 512);
        const half8 bl2 = *(const half8*)(wkl + 1024);
        const half8 bl3 = *(const half8*)(wkl + 1536);

        const float dy = offlds[(2 * kk) * 64 + pxl];      // broadcast reads
        const float dx = offlds[(2 * kk + 1) * 64 + pxl];
        const float py = (float)(h0 + kk / 3 - 1) + dy;
        const float qx = (float)(wc_ + kk % 3 - 1) + dx;
        const float y0f = floorf(py), x0f = floorf(qx);
        const float wy = py - y0f, wx = qx - x0f;
        const int iy0 = (int)y0f, ix0 = (int)x0f;
        const int iy1 = iy0 + 1,  ix1 = ix0 + 1;
        const float vy0 = (iy0 >= 0 && iy0 < H_) ? 1.f : 0.f;
        const float vy1 = (iy1 >= 0 && iy1 < H_) ? 1.f : 0.f;
        const float vx0 = (ix0 >= 0 && ix0 < W_) ? 1.f : 0.f;
        const float vx1 = (ix1 >= 0 && ix1 < W_) ? 1.f : 0.f;
        const float w00 = (1.f - wy) * (1.f - wx) * vy0 * vx0;
        const float w01 = (1.f - wy) * wx * vy0 * vx1;
        const float w10 = wy * (1.f - wx) * vy1 * vx0;
        const float w11 = wy * wx * vy1 * vx1;
        const int cy0 = min(max(iy0, 0), H_ - 1), cy1 = min(max(iy1, 0), H_ - 1);
        const int cx0 = min(max(ix0, 0), W_ - 1), cx1 = min(max(ix1, 0), W_ - 1);
        const int o00 = (cy0 * W_ + cx0) * 32, o01 = (cy0 * W_ + cx1) * 32;
        const int o10 = (cy1 * W_ + cx0) * 32, o11 = (cy1 * W_ + cx1) * 32;

        // wave covers 16 px x 32 ch: each corner spans a contiguous 2KB
        const float4 A0 = *(const float4*)(xg + o00), A1 = *(const float4*)(xg + o00 + 4);
        const float4 B0 = *(const float4*)(xg + o01), B1 = *(const float4*)(xg + o01 + 4);
        const float4 C0 = *(const float4*)(xg + o10), C1 = *(const float4*)(xg + o10 + 4);
        const float4 D0 = *(const float4*)(xg + o11), D1 = *(const float4*)(xg + o11 + 4);

        float v[8];
        v[0] = w00 * A0.x + w01 * B0.x + w10 * C0.x + w11 * D0.x;
        v[1] = w00 * A0.y + w01 * B0.y + w10 * C0.y + w11 * D0.y;
        v[2] = w00 * A0.z + w01 * B0.z + w10 * C0.z + w11 * D0.z;
        v[3] = w00 * A0.w + w01 * B0.w + w10 * C0.w + w11 * D0.w;
        v[4] = w00 * A1.x + w01 * B1.x + w10 * C1.x + w11 * D1.x;
        v[5] = w00 * A1.y + w01 * B1.y + w10 * C1.y + w11 * D1.y;
        v[6] = w00 * A1.z + w01 * B1.z + w10 * C1.z + w11 * D1.z;
        v[7] = w00 * A1.w + w01 * B1.w + w10 * C1.w + w11 * D1.w;

        half8 a_hi, a_lo;
#pragma unroll
        for (int j = 0; j < 8; ++j) {
            const _Float16 h = (_Float16)v[j];
            a_hi[j] = h;
            a_lo[j] = (_Float16)(v[j] - (float)h);
        }

        acc[0] = __builtin_amdgcn_mfma_f32_16x16x32_f16(a_hi, bh0, acc[0], 0, 0, 0);
        acc[1] = __builtin_amdgcn_mfma_f32_16x16x32_f16(a_hi, bh1, acc[1], 0, 0, 0);
        acc[2] = __builtin_amdgcn_mfma_f32_16x16x32_f16(a_hi, bh2, acc[2], 0, 0, 0);
        acc[3] = __builtin_amdgcn_mfma_f32_16x16x32_f16(a_hi, bh3, acc[3], 0, 0, 0);
        acc[0] = __builtin_amdgcn_mfma_f32_16x16x32_f16(a_lo, bh0, acc[0], 0, 0, 0);
        acc[1] = __builtin_amdgcn_mfma_f32_16x16x32_f16(a_lo, bh1, acc[1], 0, 0, 0);
        acc[2] = __builtin_amdgcn_mfma_f32_16x16x32_f16(a_lo, bh2, acc[2], 0, 0, 0);
        acc[3] = __builtin_amdgcn_mfma_f32_16x16x32_f16(a_lo, bh3, acc[3], 0, 0, 0);
        acc[0] = __builtin_amdgcn_mfma_f32_16x16x32_f16(a_hi, bl0, acc[0], 0, 0, 0);
        acc[1] = __builtin_amdgcn_mfma_f32_16x16x32_f16(a_hi, bl1, acc[1], 0, 0, 0);
        acc[2] = __builtin_amdgcn_mfma_f32_16x16x32_f16(a_hi, bl2, acc[2], 0, 0, 0);
        acc[3] = __builtin_amdgcn_mfma_f32_16x16x32_f16(a_hi, bl3, acc[3], 0, 0, 0);
    }

    // epilogue: bias + float4 store + BN stats.
    // D layout: col = lane&15 -> o = ot*16+l15; row = lq4*4+reg -> px.
    const int rem = rem0 + (og << 4) + (lq4 << 2);
    float sred[4], qred[4];
#pragma unroll
    for (int ot = 0; ot < 4; ++ot) {
        const float bias = b_def[ot * 16 + l15];
        f32x4 av = acc[ot];
        av[0] += bias; av[1] += bias; av[2] += bias; av[3] += bias;
        *(f32x4*)(y + ((size_t)(b * COUT_ + ot * 16 + l15)) * HW_ + rem) = av;
        float s = av[0] + av[1] + av[2] + av[3];
        float q = av[0] * av[0] + av[1] * av[1] + av[2] * av[2] + av[3] * av[3];
        s += __shfl_xor(s, 16, 64); s += __shfl_xor(s, 32, 64);
        q += __shfl_xor(q, 16, 64); q += __shfl_xor(q, 32, 64);
        sred[ot] = s; qred[ot] = q;
    }
    // lane (= lq4*16+l15) takes ot = lq4 -> one value pair per lane (ch = lane)
    float ms = sred[0], mq = qred[0];
    if (lq4 == 1)      { ms = sred[1]; mq = qred[1]; }
    else if (lq4 == 2) { ms = sred[2]; mq = qred[2]; }
    else if (lq4 == 3) { ms = sred[3]; mq = qred[3]; }

    // cross-wave LDS reduce -> wave 0 -> 8x-sliced atomics (the R6 fix)
    red_s[(og << 6) + lane] = ms;
    red_q[(og << 6) + lane] = mq;
    __syncthreads();
    if (og == 0) {
        const float s = red_s[lane] + red_s[64 + lane]
                      + red_s[128 + lane] + red_s[192 + lane];
        const float q = red_q[lane] + red_q[64 + lane]
                      + red_q[128 + lane] + red_q[192 + lane];
        const int slot = ((blockIdx.x & 7) << 8) + (b << 6) + lane;
        atomicAdd(&sum_bc[slot], s);
        atomicAdd(&sumsq_bc[slot], q);
    }
}

// ---------------------------------------------------------------------------
// Kernel 2: fused SE-MLP + affine(BN*SE) + ReLU + 2x2 maxpool.
// Stats now arrive 8-sliced: sum_part[8][4][64].
// ---------------------------------------------------------------------------
__global__ __launch_bounds__(256) void k_finish(
    const float* __restrict__ y,
    const float* __restrict__ sum_bc, const float* __restrict__ sumsq_bc,
    const float* __restrict__ gamma, const float* __restrict__ beta,
    const float* __restrict__ fc1_w, const float* __restrict__ fc1_b,
    const float* __restrict__ fc2_w, const float* __restrict__ fc2_b,
    float* __restrict__ out)
{
    __shared__ float sal[256], sbb[256], sin_[256], ssum[256], qsum[256];
    const int tid = threadIdx.x;
    {
        const int b = tid >> 6, c = tid & 63;
        float s_bc = 0.f, q_bc = 0.f;
#pragma unroll
        for (int p = 0; p < 8; ++p) {
            s_bc += sum_bc[(p << 8) + tid];
            q_bc += sumsq_bc[(p << 8) + tid];
        }
        ssum[tid] = s_bc; qsum[tid] = q_bc;
        __syncthreads();
        const float ch_s = ssum[c] + ssum[64 + c] + ssum[128 + c] + ssum[192 + c];
        const float ch_q = qsum[c] + qsum[64 + c] + qsum[128 + c] + qsum[192 + c];
        const float invN = 1.f / (float)(B_ * HW_);
        const float mean = ch_s * invN;
        const float var  = ch_q * invN - mean * mean;
        const float a    = gamma[c] * rsqrtf(var + EPS_);
        const float bi   = beta[c] - mean * a;
        sin_[tid] = a * (s_bc * (1.f / (float)HW_)) + bi;
        __syncthreads();
        float hv[4];
#pragma unroll
        for (int j = 0; j < 4; ++j) {
            float hs = fc1_b[j];
            for (int cc = 0; cc < 64; ++cc)
                hs += sin_[b * 64 + cc] * fc1_w[j * 64 + cc];
            hv[j] = fmaxf(hs, 0.f);
        }
        float o = fc2_b[c];
#pragma unroll
        for (int j = 0; j < 4; ++j) o += hv[j] * fc2_w[c * 4 + j];
        const float s = 1.f / (1.f + expf(-o));
        sal[tid] = a * s;
        sbb[tid] = bi * s;
    }
    __syncthreads();

    const int t    = blockIdx.x * 256 + tid;
    const int opix = t * 2;
    const int bc   = opix / (96 * 96);
    const int rem  = opix - bc * (96 * 96);
    const int oh   = rem / 96, ow = rem - oh * 96;   // ow even
    const float al = sal[bc], bb = sbb[bc];
    const float* yp = y + (size_t)bc * HW_ + (2 * oh) * W_ + 2 * ow;
    const float4 r0 = *(const float4*)yp;
    const float4 r1 = *(const float4*)(yp + W_);
    float2 st;
    st.x = fmaxf(fmaxf(fmaxf(fmaf(r0.x, al, bb), fmaf(r0.y, al, bb)),
                       fmaxf(fmaf(r1.x, al, bb), fmaf(r1.y, al, bb))), 0.f);
    st.y = fmaxf(fmaxf(fmaxf(fmaf(r0.z, al, bb), fmaf(r0.w, al, bb)),
                       fmaxf(fmaf(r1.z, al, bb), fmaf(r1.w, al, bb))), 0.f);
    *(float2*)(out + opix) = st;
}

// ---------------------------------------------------------------------------
extern "C" void kernel_launch(void* const* d_in, const int* in_sizes, int n_in,
                              void* d_out, int out_size, void* d_ws, size_t ws_size,
                              hipStream_t stream)
{
    const float* x     = (const float*)d_in[0];
    const float* w_off = (const float*)d_in[1];
    const float* b_off = (const float*)d_in[2];
    const float* w_def = (const float*)d_in[3];
    const float* b_def = (const float*)d_in[4];
    const float* gamma = (const float*)d_in[5];
    const float* beta  = (const float*)d_in[6];
    const float* fc1_w = (const float*)d_in[7];
    const float* fc1_b = (const float*)d_in[8];
    const float* fc2_w = (const float*)d_in[9];
    const float* fc2_b = (const float*)d_in[10];
    float* out = (float*)d_out;

    float* ws   = (float*)d_ws;
    float* yb        = ws;                       // 9,437,184 floats
    float* xt        = yb + 9437184;             // 4,718,592 floats (NHWC x)
    _Float16* wt_def = (_Float16*)(xt + 4718592);// 2*18,432 halves (= 18,432 floats)
    float* wt_off    = xt + 4718592 + 18432;     // 5,760
    float* stats     = wt_off + 5760;            // 4,096 (8-sliced)
    float* sum_bc    = stats;                    // [8][4][64]
    float* sumsq_bc  = stats + 2048;             // [8][4][64]

    k_pre   <<<dim3(NPIX_ / 256 + 111), dim3(256), 0, stream>>>(
                x, w_def, w_off, xt, wt_def, wt_off, stats);
    k_fused <<<dim3(NPIX_ / 64), dim3(256), 0, stream>>>(
                xt, wt_off, b_off, wt_def, b_def, yb, sum_bc, sumsq_bc);
    k_finish<<<dim3(B_ * COUT_ * 96 * 96 / 512), dim3(256), 0, stream>>>(
                yb, sum_bc, sumsq_bc, gamma, beta,
                fc1_w, fc1_b, fc2_w, fc2_b, out);
}